// Round 4
// baseline (1861.541 us; speedup 1.0000x reference)
//
#include <hip/hip_runtime.h>

// ConvLSTM on MI355X — round 4.
// Round-3 post-mortem: asm pins + 128-VGPR budget => weights spilled to scratch,
// reloaded per step (regression). Fix: amdgpu_waves_per_eu(2,2) forces a
// 2-waves/EU register target (256 VGPRs/wave) so the 144-VGPR weight set plus
// accumulators actually stays resident. Otherwise identical to round 3
// (bit-correct there), ZST back to 104 (136 was measured null).

#define Bb 32
#define Tt 128
#define Cc 32
#define Ss 256
#define Hh 64
#define ZST 104  // Z row stride in u16 (208 B)

typedef __bf16 bf16x8 __attribute__((ext_vector_type(8)));
typedef short  short8 __attribute__((ext_vector_type(8)));
typedef float  f32x4  __attribute__((ext_vector_type(4)));
typedef unsigned short u16;
typedef unsigned int   u32;

__device__ __forceinline__ u16 f2bf(float f) {
    u32 u = __float_as_uint(f);
    u = (u + 0x7FFFu + ((u >> 16) & 1u)) >> 16;  // RNE
    return (u16)u;
}
__device__ __forceinline__ float fsig(float x) {
    float e = __expf(-x);
    return __builtin_amdgcn_rcpf(1.0f + e);
}
__device__ __forceinline__ float ftanh_(float x) {
    float e = __expf(2.0f * x);
    return 1.0f - 2.0f * __builtin_amdgcn_rcpf(e + 1.0f);
}
__device__ __forceinline__ u32 cvtpk(float lo, float hi) {
    u32 d;
    asm("v_cvt_pk_bf16_f32 %0, %1, %2" : "=v"(d) : "v"(lo), "v"(hi));
    return d;
}

// ---------------- transpose: x (B,T,C,S) f32 -> xT (B,S,T*C) bf16 ----------------
__global__ __launch_bounds__(256) void xpose_kernel(const float* __restrict__ x,
                                                    u16* __restrict__ xT) {
    __shared__ u16 tile[64][130];
    const int tc0 = blockIdx.x * 128;
    const int s0  = blockIdx.y * 64;
    const int b   = blockIdx.z;
    const int tid = threadIdx.x;
    const float* xb = x + (size_t)b * (Tt * Cc * Ss);
#pragma unroll
    for (int i = 0; i < 32; ++i) {
        const int tcr = (tid >> 6) + 4 * i;
        const int sr  = tid & 63;
        tile[sr][tcr] = f2bf(xb[(size_t)(tc0 + tcr) * Ss + s0 + sr]);
    }
    __syncthreads();
    u32* xTo = (u32*)(xT + (size_t)b * (Ss * Tt * Cc));
#pragma unroll
    for (int j = 0; j < 16; ++j) {
        const int sw = (tid >> 6) + 4 * j;
        const int tw = (tid & 63) * 2;
        xTo[(((size_t)(s0 + sw)) * (Tt * Cc) + tc0 + tw) >> 1] = *(const u32*)&tile[sw][tw];
    }
}

// ---------------- recurrent kernel: one block per batch ----------------
__global__ __launch_bounds__(512)
__attribute__((amdgpu_waves_per_eu(2, 2)))
void convlstm4_kernel(
    const float* __restrict__ Wc, const float* __restrict__ bc,
    const float* __restrict__ Wl, const float* __restrict__ bl,
    const u16* __restrict__ xT, float* __restrict__ out) {

    // Z: rows 0..129 = t -1..128 (halo rows stay zero), cols 0..31 x, 32..95 h, 96..103 pad
    __shared__ u16  zbuf[2][130][ZST];
    __shared__ float red[2][8][16];

    const int b    = blockIdx.x;
    const int tid  = threadIdx.x;
    const int w    = tid >> 6;     // wave 0..7
    const int lane = tid & 63;
    const int l15  = lane & 15;
    const int q    = lane >> 4;
    const int ht   = w >> 1;       // 16 h-rows tile
    const int th   = w & 1;        // t-half

    {   // zero both Z buffers (halos + h(-1) = 0)
        u32* z32 = (u32*)&zbuf[0][0][0];
        for (int i = tid; i < (2 * 130 * ZST) / 2; i += 512) z32[i] = 0;
    }

    // weight fragments, resident: afr[gate][tap][ks]; k-slot j -> ch 32*ks+8*q+j
    bf16x8 afr[4][3][3];
#pragma unroll
    for (int g = 0; g < 4; ++g)
#pragma unroll
        for (int k = 0; k < 3; ++k)
#pragma unroll
            for (int ks = 0; ks < 3; ++ks) {
                const int gc = 64 * g + 16 * ht + l15;
                short8 t;
#pragma unroll
                for (int j = 0; j < 8; ++j)
                    t[j] = (short)f2bf(Wc[gc * 288 + (32 * ks + 8 * q + j) * 3 + k]);
                f32x4 kv = __builtin_bit_cast(f32x4, t);
                asm volatile("" : "+v"(kv));          // opaque def: no remat
                afr[g][k][ks] = __builtin_bit_cast(bf16x8, kv);
            }

    // bias (acc-init) and Wl
    f32x4 bcv[4];
#pragma unroll
    for (int g = 0; g < 4; ++g) {
        bcv[g] = *(const f32x4*)&bc[64 * g + 16 * ht + 4 * q];
        asm volatile("" : "+v"(bcv[g]));
    }
    float wlv[4];
#pragma unroll
    for (int nj = 0; nj < 4; ++nj) {
        wlv[nj] = Wl[64 * th + 16 * nj + l15];
        asm volatile("" : "+v"(wlv[nj]));
    }
    const float bl0 = bl[0];

    float cst[16];
#pragma unroll
    for (int i = 0; i < 16; ++i) cst[i] = 0.0f;

    // x staging: thread -> (t = tid>>2, c0 = (tid&3)*8)
    const int xt = tid >> 2;
    const int xc = (tid & 3) * 8;
    const u16* xTb = xT + (size_t)b * (Ss * Tt * Cc);

    // prime x(0) into buffer 1 (step 0 reads zbuf[1])
    {
        uint4 xv0 = *(const uint4*)(xTb + xt * 32 + xc);
        __syncthreads();  // zeroing complete
        *(uint4*)&zbuf[1][1 + xt][xc] = xv0;
        __syncthreads();  // x(0) visible
    }

    float* outb = out + (size_t)b * (Ss * Hh);

    for (int s = 0; s < Ss; ++s) {
        // prefetch x(s+1)
        uint4 xv;
        const bool havex = (s + 1) < Ss;
        if (havex) xv = *(const uint4*)(xTb + (size_t)(s + 1) * (Tt * Cc) + xt * 32 + xc);

        // emit output for step s-1 (red double-buffered)
        if (tid < 64 && s > 0) {
            const int ps = (s - 1) & 1;
            float v = red[ps][(tid >> 4) * 2][tid & 15] + red[ps][(tid >> 4) * 2 + 1][tid & 15] + bl0;
            outb[(size_t)(s - 1) * Hh + tid] = fsig(v);
        }

        const u16 (*zb)[ZST] = zbuf[(s & 1) ^ 1];  // [x(s); h(s-1)]
        u16 (*zn)[ZST] = zbuf[s & 1];              // gets h(s), x(s+1)

        float partial[4] = {0.f, 0.f, 0.f, 0.f};
        f32x4 acc[2][4];

#pragma unroll
        for (int c = 0; c < 5; ++c) {
            if (c < 4) {
                // acc(c) init = bias; MFMAs for chunk nj = c (K = 96ch x 3 taps)
#pragma unroll
                for (int g = 0; g < 4; ++g) acc[c & 1][g] = bcv[g];
                const int tb = 64 * th + 16 * c + l15;
#pragma unroll
                for (int k = 0; k < 3; ++k)
#pragma unroll
                    for (int ks = 0; ks < 3; ++ks) {
                        bf16x8 bfr = *(const bf16x8*)&zb[tb + k][32 * ks + 8 * q];
                        acc[c & 1][0] = __builtin_amdgcn_mfma_f32_16x16x32_bf16(afr[0][k][ks], bfr, acc[c & 1][0], 0, 0, 0);
                        acc[c & 1][1] = __builtin_amdgcn_mfma_f32_16x16x32_bf16(afr[1][k][ks], bfr, acc[c & 1][1], 0, 0, 0);
                        acc[c & 1][2] = __builtin_amdgcn_mfma_f32_16x16x32_bf16(afr[2][k][ks], bfr, acc[c & 1][2], 0, 0, 0);
                        acc[c & 1][3] = __builtin_amdgcn_mfma_f32_16x16x32_bf16(afr[3][k][ks], bfr, acc[c & 1][3], 0, 0, 0);
                    }
            }
            if (c > 0) {  // gates for chunk c-1, in the MFMA shadow of chunk c
                const int nj = c - 1;
                float hv[4];
#pragma unroll
                for (int r = 0; r < 4; ++r) {
                    const float ig = fsig(acc[nj & 1][0][r]);
                    const float fg = fsig(acc[nj & 1][1][r]);
                    const float og = fsig(acc[nj & 1][2][r]);
                    const float gg = ftanh_(acc[nj & 1][3][r]);
                    const float cv = fg * cst[nj * 4 + r] + ig * gg;
                    cst[nj * 4 + r] = cv;
                    hv[r] = og * ftanh_(cv);
                    partial[r] += hv[r] * wlv[nj];
                }
                uint2 hw;
                hw.x = cvtpk(hv[0], hv[1]);
                hw.y = cvtpk(hv[2], hv[3]);
                // h channel = 16*ht + 4*q + r -> Z col 32 + that
                *(uint2*)&zn[1 + 64 * th + 16 * nj + l15][32 + 16 * ht + 4 * q] = hw;
            }
        }

        // write prefetched x(s+1)
        if (havex) *(uint4*)&zn[1 + xt][xc] = xv;

        // reduce output partials over the 16 t-lanes of each quarter
#pragma unroll
        for (int r = 0; r < 4; ++r) {
#pragma unroll
            for (int offl = 1; offl <= 8; offl <<= 1)
                partial[r] += __shfl_xor(partial[r], offl, 64);
        }
        if (l15 == 0) {
#pragma unroll
            for (int r = 0; r < 4; ++r) red[s & 1][w][4 * q + r] = partial[r];
        }
        __syncthreads();  // h(s), x(s+1), red(s) visible — ONE barrier per step
    }

    if (tid < 64) {  // final output, s = Ss-1
        const int ps = (Ss - 1) & 1;
        float v = red[ps][(tid >> 4) * 2][tid & 15] + red[ps][(tid >> 4) * 2 + 1][tid & 15] + bl0;
        outb[(size_t)(Ss - 1) * Hh + tid] = fsig(v);
    }
}

extern "C" void kernel_launch(void* const* d_in, const int* in_sizes, int n_in,
                              void* d_out, int out_size, void* d_ws, size_t ws_size,
                              hipStream_t stream) {
    const float* x  = (const float*)d_in[0];
    const float* Wc = (const float*)d_in[1];
    const float* bc = (const float*)d_in[2];
    const float* Wl = (const float*)d_in[3];
    const float* bl = (const float*)d_in[4];
    float* out = (float*)d_out;
    u16*   xT  = (u16*)d_ws;  // 64 MiB (proven available)

    dim3 tgrid(Tt * Cc / 128, Ss / 64, Bb);
    xpose_kernel<<<tgrid, 256, 0, stream>>>(x, xT);
    convlstm4_kernel<<<Bb, 512, 0, stream>>>(Wc, bc, Wl, bl, xT, out);
}

// Round 5
// 1374.729 us; speedup vs baseline: 1.3541x; 1.3541x over previous
//
#include <hip/hip_runtime.h>

// ConvLSTM on MI355X — round 5.
// r3/r4 post-mortem: allocator pins a 128-VGPR budget; forcing residency of the
// 144-VGPR weight set only produces scratch spills (regression). New approach:
// make per-step weight access cheap instead of resident. wprep_kernel
// pre-converts Wc to bf16 fragments in the exact per-lane layout; the recurrent
// kernel loads them in-loop as b128 (no f2bf VALU, short live ranges, VMEM pipe
// idle otherwise). Bias as register acc-init. Structure otherwise = round-1
// (bit-proven). ws_size guard -> round-1 fallback kernel.

#define Bb 32
#define Tt 128
#define Cc 32
#define Ss 256
#define Hh 64
#define ZST 104

typedef __bf16 bf16x8 __attribute__((ext_vector_type(8)));
typedef short  short8 __attribute__((ext_vector_type(8)));
typedef float  f32x4  __attribute__((ext_vector_type(4)));
typedef unsigned short u16;
typedef unsigned int   u32;

__device__ __forceinline__ u16 f2bf(float f) {
    u32 u = __float_as_uint(f);
    u = (u + 0x7FFFu + ((u >> 16) & 1u)) >> 16;  // RNE
    return (u16)u;
}
__device__ __forceinline__ float fsig(float x) {
    float e = __expf(-x);
    return __builtin_amdgcn_rcpf(1.0f + e);
}
__device__ __forceinline__ float ftanh_(float x) {
    float e = __expf(2.0f * x);
    return 1.0f - 2.0f * __builtin_amdgcn_rcpf(e + 1.0f);
}

// ---------------- transpose: x (B,T,C,S) f32 -> xT (B,S,T*C) bf16 ----------------
__global__ __launch_bounds__(256) void xpose_kernel(const float* __restrict__ x,
                                                    u16* __restrict__ xT) {
    __shared__ u16 tile[64][130];
    const int tc0 = blockIdx.x * 128;
    const int s0  = blockIdx.y * 64;
    const int b   = blockIdx.z;
    const int tid = threadIdx.x;
    const float* xb = x + (size_t)b * (Tt * Cc * Ss);
#pragma unroll
    for (int i = 0; i < 32; ++i) {
        const int tcr = (tid >> 6) + 4 * i;
        const int sr  = tid & 63;
        tile[sr][tcr] = f2bf(xb[(size_t)(tc0 + tcr) * Ss + s0 + sr]);
    }
    __syncthreads();
    u32* xTo = (u32*)(xT + (size_t)b * (Ss * Tt * Cc));
#pragma unroll
    for (int j = 0; j < 16; ++j) {
        const int sw = (tid >> 6) + 4 * j;
        const int tw = (tid & 63) * 2;
        xTo[(((size_t)(s0 + sw)) * (Tt * Cc) + tc0 + tw) >> 1] = *(const u32*)&tile[sw][tw];
    }
}

// ---------------- weight prep: Wc f32 -> wpre[ht][f=(g*9+k*3+ks)][lane][8] bf16 ----------------
__global__ __launch_bounds__(256) void wprep_kernel(const float* __restrict__ Wc,
                                                    u16* __restrict__ wpre) {
    const int ht  = blockIdx.x;   // 0..3
    const int tid = threadIdx.x;
#pragma unroll
    for (int it = 0; it < 9; ++it) {
        const int idx  = it * 256 + tid;      // 0..2303
        const int f    = idx >> 6;            // 0..35
        const int lane = idx & 63;
        const int g  = f / 9;
        const int k  = (f % 9) / 3;
        const int ks = f % 3;
        const int l15 = lane & 15;
        const int q   = lane >> 4;
        const int gc  = 64 * g + 16 * ht + l15;
        u16 tmp[8];
#pragma unroll
        for (int j = 0; j < 8; ++j)
            tmp[j] = f2bf(Wc[gc * 288 + (32 * ks + 8 * q + j) * 3 + k]);
        *(uint4*)(wpre + ((size_t)(ht * 36 + f) * 64 + lane) * 8) = *(const uint4*)tmp;
    }
}

// ---------------- recurrent kernel: one block per batch ----------------
__global__ __launch_bounds__(512) void convlstm5_kernel(
    const float* __restrict__ bc, const float* __restrict__ Wl,
    const float* __restrict__ bl, const u16* __restrict__ xT,
    const u16* __restrict__ wpre, float* __restrict__ out) {

    __shared__ u16  zbuf[2][130][ZST];  // rows t=-1..128, cols 0..31 x, 32..95 h
    __shared__ float red[8][16];

    const int b    = blockIdx.x;
    const int tid  = threadIdx.x;
    const int w    = tid >> 6;
    const int lane = tid & 63;
    const int l15  = lane & 15;
    const int q    = lane >> 4;
    const int ht   = w >> 1;
    const int th   = w & 1;

    {
        u32* z32 = (u32*)&zbuf[0][0][0];
        for (int i = tid; i < (2 * 130 * ZST) / 2; i += 512) z32[i] = 0;
    }

    // per-lane weight base (bf16 fragments, precomputed)
    const u16* wlp = wpre + (size_t)ht * 18432 + lane * 8;

    // bias acc-init and Wl (small register sets; allocator free to handle)
    f32x4 bcv[4];
#pragma unroll
    for (int g = 0; g < 4; ++g) bcv[g] = *(const f32x4*)&bc[64 * g + 16 * ht + 4 * q];
    float wlv[4];
#pragma unroll
    for (int nj = 0; nj < 4; ++nj) wlv[nj] = Wl[64 * th + 16 * nj + l15];
    const float bl0 = bl[0];

    float cst[16];
#pragma unroll
    for (int i = 0; i < 16; ++i) cst[i] = 0.0f;

    const int xt = tid >> 2;
    const int xc = (tid & 3) * 8;
    const u16* xTb = xT + (size_t)b * (Ss * Tt * Cc);

    {
        uint4 xv0 = *(const uint4*)(xTb + xt * 32 + xc);
        __syncthreads();
        *(uint4*)&zbuf[0][1 + xt][xc] = xv0;
        __syncthreads();
    }

    float* outb = out + (size_t)b * (Ss * Hh);
    int p = 0;

    for (int s = 0; s < Ss; ++s) {
        uint4 xv;
        const bool havex = (s + 1) < Ss;
        if (havex) xv = *(const uint4*)(xTb + (size_t)(s + 1) * (Tt * Cc) + xt * 32 + xc);

        if (tid < 64 && s > 0) {
            float v = red[(tid >> 4) * 2][tid & 15] + red[(tid >> 4) * 2 + 1][tid & 15] + bl0;
            outb[(size_t)(s - 1) * Hh + tid] = fsig(v);
        }
        __syncthreads();  // barrier A

        const u16 (*zb)[ZST] = zbuf[p];
        u16 (*zn)[ZST] = zbuf[p ^ 1];

        float partial[4] = {0.f, 0.f, 0.f, 0.f};

#pragma unroll
        for (int half = 0; half < 2; ++half) {
            f32x4 acc[4][2];
#pragma unroll
            for (int g = 0; g < 4; ++g) {
                acc[g][0] = bcv[g];
                acc[g][1] = bcv[g];
            }

            // weight group double-buffer: 4 gate frags per (k,ks)
            bf16x8 wf[2][4];
#pragma unroll
            for (int g = 0; g < 4; ++g)
                wf[0][g] = *(const bf16x8*)(wlp + (size_t)(g * 9) * 512);

#pragma unroll
            for (int kk = 0; kk < 9; ++kk) {   // kk = k*3 + ks
                const int k  = kk / 3;
                const int ks = kk % 3;
                const int cur = kk & 1;
                if (kk < 8) {
#pragma unroll
                    for (int g = 0; g < 4; ++g)
                        wf[cur ^ 1][g] = *(const bf16x8*)(wlp + (size_t)(g * 9 + kk + 1) * 512);
                }
#pragma unroll
                for (int njl = 0; njl < 2; ++njl) {
                    const int nj = half * 2 + njl;
                    const int tb = 64 * th + 16 * nj + l15;
                    bf16x8 bfr = *(const bf16x8*)&zb[tb + k][32 * ks + 8 * q];
                    acc[0][njl] = __builtin_amdgcn_mfma_f32_16x16x32_bf16(wf[cur][0], bfr, acc[0][njl], 0, 0, 0);
                    acc[1][njl] = __builtin_amdgcn_mfma_f32_16x16x32_bf16(wf[cur][1], bfr, acc[1][njl], 0, 0, 0);
                    acc[2][njl] = __builtin_amdgcn_mfma_f32_16x16x32_bf16(wf[cur][2], bfr, acc[2][njl], 0, 0, 0);
                    acc[3][njl] = __builtin_amdgcn_mfma_f32_16x16x32_bf16(wf[cur][3], bfr, acc[3][njl], 0, 0, 0);
                }
            }

#pragma unroll
            for (int njl = 0; njl < 2; ++njl) {
                const int nj = half * 2 + njl;
                u16 hp[4];
#pragma unroll
                for (int r = 0; r < 4; ++r) {
                    const float ig = fsig(acc[0][njl][r]);
                    const float fg = fsig(acc[1][njl][r]);
                    const float og = fsig(acc[2][njl][r]);
                    const float gg = ftanh_(acc[3][njl][r]);
                    const float cv = fg * cst[nj * 4 + r] + ig * gg;
                    cst[nj * 4 + r] = cv;
                    const float hv = og * ftanh_(cv);
                    partial[r] += hv * wlv[nj];
                    hp[r] = f2bf(hv);
                }
                uint2 hw;
                hw.x = (u32)hp[0] | ((u32)hp[1] << 16);
                hw.y = (u32)hp[2] | ((u32)hp[3] << 16);
                *(uint2*)&zn[1 + 64 * th + 16 * nj + l15][32 + 16 * ht + 4 * q] = hw;
            }
        }

        if (havex) *(uint4*)&zn[1 + xt][xc] = xv;

#pragma unroll
        for (int r = 0; r < 4; ++r) {
#pragma unroll
            for (int offl = 1; offl <= 8; offl <<= 1)
                partial[r] += __shfl_xor(partial[r], offl, 64);
        }
        if (l15 == 0) {
#pragma unroll
            for (int r = 0; r < 4; ++r) red[w][4 * q + r] = partial[r];
        }
        __syncthreads();  // barrier B
        p ^= 1;
    }

    if (tid < 64) {
        float v = red[(tid >> 4) * 2][tid & 15] + red[(tid >> 4) * 2 + 1][tid & 15] + bl0;
        outb[(size_t)(Ss - 1) * Hh + tid] = fsig(v);
    }
}

// ---------------- round-1 fallback (proven; used if ws too small) ----------------
__global__ __launch_bounds__(512, 2) void convlstm_kernel(
    const float* __restrict__ Wc, const float* __restrict__ bc,
    const float* __restrict__ Wl, const float* __restrict__ bl,
    const u16* __restrict__ xT, float* __restrict__ out) {

    __shared__ u16  zbuf[2][130][ZST];
    __shared__ float red[8][16];
    __shared__ float bcl[256];

    const int b    = blockIdx.x;
    const int tid  = threadIdx.x;
    const int w    = tid >> 6;
    const int lane = tid & 63;
    const int l15  = lane & 15;
    const int q    = lane >> 4;
    const int ht   = w >> 1;
    const int th   = w & 1;

    {
        u32* z32 = (u32*)&zbuf[0][0][0];
        for (int i = tid; i < (2 * 130 * ZST) / 2; i += 512) z32[i] = 0;
    }
    if (tid < 256) bcl[tid] = bc[tid];

    bf16x8 afr[4][3][3];
#pragma unroll
    for (int g = 0; g < 4; ++g)
#pragma unroll
        for (int k = 0; k < 3; ++k)
#pragma unroll
            for (int ks = 0; ks < 3; ++ks) {
                const int gc = 64 * g + 16 * ht + l15;
                short8 t;
#pragma unroll
                for (int j = 0; j < 8; ++j)
                    t[j] = (short)f2bf(Wc[gc * 288 + (32 * ks + 8 * q + j) * 3 + k]);
                afr[g][k][ks] = __builtin_bit_cast(bf16x8, t);
            }

    float wlv[4];
#pragma unroll
    for (int nj = 0; nj < 4; ++nj) wlv[nj] = Wl[64 * th + 16 * nj + l15];
    const float bl0 = bl[0];

    float cst[16];
#pragma unroll
    for (int i = 0; i < 16; ++i) cst[i] = 0.0f;

    const int xt = tid >> 2;
    const int xc = (tid & 3) * 8;
    const u16* xTb = xT + (size_t)b * (Ss * Tt * Cc);

    {
        uint4 xv0 = *(const uint4*)(xTb + xt * 32 + xc);
        __syncthreads();
        *(uint4*)&zbuf[0][1 + xt][xc] = xv0;
        __syncthreads();
    }

    float* outb = out + (size_t)b * (Ss * Hh);
    int p = 0;

    for (int s = 0; s < Ss; ++s) {
        uint4 xv;
        const bool havex = (s + 1) < Ss;
        if (havex) xv = *(const uint4*)(xTb + (size_t)(s + 1) * (Tt * Cc) + xt * 32 + xc);

        if (tid < 64 && s > 0) {
            float v = red[(tid >> 4) * 2][tid & 15] + red[(tid >> 4) * 2 + 1][tid & 15] + bl0;
            outb[(size_t)(s - 1) * Hh + tid] = fsig(v);
        }
        __syncthreads();

        const u16 (*zb)[ZST] = zbuf[p];
        u16 (*zn)[ZST] = zbuf[p ^ 1];

        float partial[4] = {0.f, 0.f, 0.f, 0.f};

#pragma unroll
        for (int half = 0; half < 2; ++half) {
            f32x4 acc[4][2];
#pragma unroll
            for (int g = 0; g < 4; ++g) {
                acc[g][0] = (f32x4){0.f, 0.f, 0.f, 0.f};
                acc[g][1] = (f32x4){0.f, 0.f, 0.f, 0.f};
            }
#pragma unroll
            for (int njl = 0; njl < 2; ++njl) {
                const int nj = half * 2 + njl;
                const int tb = 64 * th + 16 * nj + l15;
#pragma unroll
                for (int k = 0; k < 3; ++k)
#pragma unroll
                    for (int ks = 0; ks < 3; ++ks) {
                        bf16x8 bfr = *(const bf16x8*)&zb[tb + k][32 * ks + 8 * q];
                        acc[0][njl] = __builtin_amdgcn_mfma_f32_16x16x32_bf16(afr[0][k][ks], bfr, acc[0][njl], 0, 0, 0);
                        acc[1][njl] = __builtin_amdgcn_mfma_f32_16x16x32_bf16(afr[1][k][ks], bfr, acc[1][njl], 0, 0, 0);
                        acc[2][njl] = __builtin_amdgcn_mfma_f32_16x16x32_bf16(afr[2][k][ks], bfr, acc[2][njl], 0, 0, 0);
                        acc[3][njl] = __builtin_amdgcn_mfma_f32_16x16x32_bf16(afr[3][k][ks], bfr, acc[3][njl], 0, 0, 0);
                    }
            }

#pragma unroll
            for (int njl = 0; njl < 2; ++njl) {
                const int nj = half * 2 + njl;
                u16 hp[4];
#pragma unroll
                for (int r = 0; r < 4; ++r) {
                    const int hl = 4 * q + r;
                    const float ig = fsig(acc[0][njl][r] + bcl[0   + 16 * ht + hl]);
                    const float fg = fsig(acc[1][njl][r] + bcl[64  + 16 * ht + hl]);
                    const float og = fsig(acc[2][njl][r] + bcl[128 + 16 * ht + hl]);
                    const float gg = ftanh_(acc[3][njl][r] + bcl[192 + 16 * ht + hl]);
                    const float cv = fg * cst[nj * 4 + r] + ig * gg;
                    cst[nj * 4 + r] = cv;
                    const float hv = og * ftanh_(cv);
                    partial[r] += hv * wlv[nj];
                    hp[r] = f2bf(hv);
                }
                uint2 hw;
                hw.x = (u32)hp[0] | ((u32)hp[1] << 16);
                hw.y = (u32)hp[2] | ((u32)hp[3] << 16);
                *(uint2*)&zn[1 + 64 * th + 16 * nj + l15][32 + 16 * ht + 4 * q] = hw;
            }
        }

        if (havex) *(uint4*)&zn[1 + xt][xc] = xv;

#pragma unroll
        for (int r = 0; r < 4; ++r) {
#pragma unroll
            for (int offl = 1; offl <= 8; offl <<= 1)
                partial[r] += __shfl_xor(partial[r], offl, 64);
        }
        if (l15 == 0) {
#pragma unroll
            for (int r = 0; r < 4; ++r) red[w][4 * q + r] = partial[r];
        }
        __syncthreads();
        p ^= 1;
    }

    if (tid < 64) {
        float v = red[(tid >> 4) * 2][tid & 15] + red[(tid >> 4) * 2 + 1][tid & 15] + bl0;
        outb[(size_t)(Ss - 1) * Hh + tid] = fsig(v);
    }
}

extern "C" void kernel_launch(void* const* d_in, const int* in_sizes, int n_in,
                              void* d_out, int out_size, void* d_ws, size_t ws_size,
                              hipStream_t stream) {
    const float* x  = (const float*)d_in[0];
    const float* Wc = (const float*)d_in[1];
    const float* bc = (const float*)d_in[2];
    const float* Wl = (const float*)d_in[3];
    const float* bl = (const float*)d_in[4];
    float* out = (float*)d_out;

    u16* xT = (u16*)d_ws;
    const size_t XT_BYTES = (size_t)Bb * Ss * Tt * Cc * 2;   // 64 MiB
    const size_t WP_BYTES = (size_t)4 * 36 * 64 * 8 * 2;     // 144 KiB

    dim3 tgrid(Tt * Cc / 128, Ss / 64, Bb);
    xpose_kernel<<<tgrid, 256, 0, stream>>>(x, xT);

    if (ws_size >= XT_BYTES + WP_BYTES) {
        u16* wpre = (u16*)((char*)d_ws + XT_BYTES);
        wprep_kernel<<<4, 256, 0, stream>>>(Wc, wpre);
        convlstm5_kernel<<<Bb, 512, 0, stream>>>(bc, Wl, bl, xT, wpre, out);
    } else {
        convlstm_kernel<<<Bb, 512, 0, stream>>>(Wc, bc, Wl, bl, xT, out);
    }
}